// Round 1
// 180.342 us; speedup vs baseline: 1.0305x; 1.0305x over previous
//
#include <hip/hip_runtime.h>
#include <math.h>

#define D_   512
#define H_   4
#define KC   128
#define T_   1024
#define B_   4
#define NEG_ -10000.0f

typedef short bf16x8 __attribute__((ext_vector_type(8)));
typedef float f32x4  __attribute__((ext_vector_type(4)));

__device__ __forceinline__ ushort f2b_rne(float x) {
    unsigned u = __float_as_uint(x);
    u += 0x7fffu + ((u >> 16) & 1u);
    return (ushort)(u >> 16);
}

// ---------------------------------------------------------------------------
// fused fp32 -> bf16 converter for all 6 tensors (one launch)
// blocks: [0,1024) x, [1024,2048) c, [2048,2560) the 4 weights (128 each)
// ---------------------------------------------------------------------------
__global__ __launch_bounds__(256) void cvt_all(const float* __restrict__ x,
                                               const float* __restrict__ c,
                                               const float* __restrict__ w0,
                                               const float* __restrict__ w1,
                                               const float* __restrict__ w2,
                                               const float* __restrict__ w3,
                                               ushort* xo, ushort* co,
                                               ushort* o0, ushort* o1,
                                               ushort* o2, ushort* o3)
{
    const int blk = blockIdx.x;
    const float* src; ushort* dst; int base;
    if (blk < 1024)      { src = x; dst = xo; base = blk; }
    else if (blk < 2048) { src = c; dst = co; base = blk - 1024; }
    else {
        const int w = (blk - 2048) >> 7;
        base = (blk - 2048) & 127;
        src = (w == 0) ? w0 : (w == 1) ? w1 : (w == 2) ? w2 : w3;
        dst = (w == 0) ? o0 : (w == 1) ? o1 : (w == 2) ? o2 : o3;
    }
    const int i = base * 256 + threadIdx.x;
    const float4 a = ((const float4*)src)[2 * i];
    const float4 b = ((const float4*)src)[2 * i + 1];
    uint4 r;
    r.x = (unsigned)f2b_rne(a.x) | ((unsigned)f2b_rne(a.y) << 16);
    r.y = (unsigned)f2b_rne(a.z) | ((unsigned)f2b_rne(a.w) << 16);
    r.z = (unsigned)f2b_rne(b.x) | ((unsigned)f2b_rne(b.y) << 16);
    r.w = (unsigned)f2b_rne(b.z) | ((unsigned)f2b_rne(b.w) << 16);
    ((uint4*)dst)[i] = r;
}

// ---------------------------------------------------------------------------
// bf16 MFMA GEMM: C = A * W^T + bias
//  mode 0: fp32 row-major [M,512]
//  mode 1: bf16 head-split [B,H,T,KC]
//  mode 2: bf16 head-split TRANSPOSED [B,H,KC,T]  (for V)
// ---------------------------------------------------------------------------
#define GB 64
#define GK 32

__global__ __launch_bounds__(256) void gemm_mfma(const ushort* __restrict__ A,
                                                 const ushort* __restrict__ W,
                                                 const float* __restrict__ bias,
                                                 void* __restrict__ Cout, int mode)
{
    __shared__ __align__(16) ushort As[GB * GK];
    __shared__ __align__(16) ushort Bs[GB * GK];

    const int tid = threadIdx.x;
    const int m0 = blockIdx.x * GB;
    const int n0 = blockIdx.y * GB;
    const int lane = tid & 63;
    const int wid  = tid >> 6;
    const int wm = (wid >> 1) * 32;
    const int wn = (wid & 1) * 32;

    const int srow = tid >> 2;
    const int skb  = (tid & 3) * 8;
    const ushort* ga = A + (size_t)(m0 + srow) * D_ + skb;
    const ushort* gb = W + (size_t)(n0 + srow) * D_ + skb;

    f32x4 acc[2][2] = {};

    const int frow = lane & 15;
    const int fq   = lane >> 4;

    for (int k0 = 0; k0 < D_; k0 += GK) {
        __syncthreads();
        __builtin_amdgcn_global_load_lds(
            (const __attribute__((address_space(1))) void*)(ga + k0),
            (__attribute__((address_space(3))) void*)(As + tid * 8), 16, 0, 0);
        __builtin_amdgcn_global_load_lds(
            (const __attribute__((address_space(1))) void*)(gb + k0),
            (__attribute__((address_space(3))) void*)(Bs + tid * 8), 16, 0, 0);
        __syncthreads();

        bf16x8 af[2], bf[2];
#pragma unroll
        for (int mt = 0; mt < 2; mt++)
            af[mt] = *(const bf16x8*)(As + ((wm + mt * 16 + frow) * 4 + fq) * 8);
#pragma unroll
        for (int nt = 0; nt < 2; nt++)
            bf[nt] = *(const bf16x8*)(Bs + ((wn + nt * 16 + frow) * 4 + fq) * 8);
#pragma unroll
        for (int mt = 0; mt < 2; mt++)
#pragma unroll
            for (int nt = 0; nt < 2; nt++)
                acc[mt][nt] = __builtin_amdgcn_mfma_f32_16x16x32_bf16(
                    af[mt], bf[nt], acc[mt][nt], 0, 0, 0);
    }

#pragma unroll
    for (int mt = 0; mt < 2; mt++)
#pragma unroll
        for (int nt = 0; nt < 2; nt++) {
            const int n = n0 + wn + nt * 16 + frow;
            const float bn = bias[n];
            const int mb = m0 + wm + mt * 16 + fq * 4;
            if (mode == 2) {
                const int b = mb >> 10, t0 = mb & (T_ - 1);
                const int h = n >> 7, kc = n & (KC - 1);
                ushort4 pk;
                pk.x = f2b_rne(acc[mt][nt][0] + bn);
                pk.y = f2b_rne(acc[mt][nt][1] + bn);
                pk.z = f2b_rne(acc[mt][nt][2] + bn);
                pk.w = f2b_rne(acc[mt][nt][3] + bn);
                *(ushort4*)((ushort*)Cout +
                    ((size_t)((b * H_ + h) * KC + kc)) * T_ + t0) = pk;
            } else {
#pragma unroll
                for (int r = 0; r < 4; r++) {
                    const int m = mb + r;
                    const float val = acc[mt][nt][r] + bn;
                    if (mode == 1) {
                        const int b = m >> 10, t = m & (T_ - 1);
                        const int h = n >> 7, kc = n & (KC - 1);
                        ((ushort*)Cout)[((size_t)((b * H_ + h) * T_ + t)) * KC + kc] =
                            f2b_rne(val);
                    } else {
                        ((float*)Cout)[(size_t)m * D_ + n] = val;
                    }
                }
            }
        }
}

// ---------------------------------------------------------------------------
// MFMA flash attention. Block = 512 thr = 8 waves; (b,h) x 64-row Q tile.
// Waves split into 2 groups of 4; group g owns column tiles {g, g+2, g+4,...}
// with private Ks/Vt/Ps/pdiag buffers and private online-softmax state.
// States merge once at the end (exact: every column is in exactly one group).
// Next tile's K/V is loaded into registers at loop top and written to LDS
// after the post-PV barrier (async-stage split: HBM latency hides under
// QK+softmax+PV). rel-k logits computed via 4 MFMAs instead of scalar loop.
// Swizzles identical to the verified previous version.
// ---------------------------------------------------------------------------
__global__ __launch_bounds__(512) void attn_mfma(const ushort* __restrict__ qg,
                                                 const ushort* __restrict__ kg,
                                                 const ushort* __restrict__ vtg,
                                                 const float* __restrict__ mask,
                                                 const float* __restrict__ relk,
                                                 const float* __restrict__ relv,
                                                 ushort* __restrict__ outp)
{
    const int bh = blockIdx.y;
    const int b  = bh >> 2;
    const int h  = bh & 3;
    const int i0 = blockIdx.x * 64;
    const int tid  = threadIdx.x;
    const int lane = tid & 63;
    const int wid  = tid >> 6;
    const int grp  = wid >> 2;        // wave group 0/1
    const int tgid = tid & 255;       // thread id within group
    const int c_   = lane & 15;
    const int quad = lane >> 4;
    const int c7   = c_ & 7;
    const int row0 = 16 * (wid & 3);

    __shared__ __align__(16) ushort Qs[64 * 128];        // 16 KB (shared)
    __shared__ __align__(16) ushort Ks2[2][64 * 128];    // 32 KB (per group)
    __shared__ __align__(16) ushort Vt2[2][64 * 128];    // 32 KB (per group) [ch][t]
    __shared__ __align__(16) ushort Ps2[2][64 * 64];     // 16 KB (per group)
    __shared__ __align__(16) ushort Krel[16 * 128];      //  4 KB (rows 9..15 unused)
    __shared__ float relv_s[9 * 128];
    __shared__ float rlog[64][9];
    __shared__ float pdiag2[2][64][9];
    __shared__ float lg[257];
    __shared__ float msk2[2][64];
    __shared__ float rowm[64];
    __shared__ float m1s[64], l1s[64];

    ushort* Ks = Ks2[grp];
    ushort* Vt = Vt2[grp];
    ushort* Ps = Ps2[grp];
    float (*pdiag)[9] = pdiag2[grp];
    float* msk = msk2[grp];

    const float scale = 0.08838834764831845f;  // 1/sqrt(128)

    // ---- one-time staging: Q tile (swizzled), tables, bf16 relk ----
#pragma unroll
    for (int s = 0; s < 2; s++) {
        const int e = s * 512 + tid;
        const int r = e >> 4;
        const int c8 = e & 15;
        const uint4 val = *(const uint4*)(qg + ((size_t)(bh * T_ + i0 + r) * KC + c8 * 8));
        *(uint4*)(Qs + r * 128 + ((c8 ^ (r & 7)) * 8)) = val;
    }
    if (tid < 64) rowm[tid] = mask[b * T_ + i0 + tid];
    for (int e = tid; e < 1152; e += 512) ((float*)pdiag2)[e] = 0.f;
    for (int e = tid; e < 1152; e += 512) relv_s[e] = relv[e];
    for (int e = tid; e < 1152; e += 512) {
        const int d = e >> 7, kk = e & 127;
        Krel[d * 128 + (((kk >> 3) ^ (d & 7)) * 8) + (kk & 7)] = f2b_rne(relk[e]);
    }
    for (int e = tid; e < 257; e += 512) lg[e] = log1pf((float)e);
    __syncthreads();

    const int cstart = (i0 - 256 > 0) ? (i0 - 256) : 0;
    const int cend   = (i0 + 64 + 256 < T_) ? (i0 + 64 + 256) : T_;
    const int ntl    = (cend - cstart) >> 6;
    const int ntt    = (ntl + 1) >> 1;   // iterations per group (ntl >= 5 always)

    // ---- prologue: issue group's first K/V tile loads ----
    uint4 kreg[4], vreg[4]; float mreg = 0.f;
    {
        const int j0n = cstart + grp * 64;
#pragma unroll
        for (int s = 0; s < 4; s++) {
            const int e = s * 256 + tgid;
            const int r = e >> 4, c8 = e & 15;
            kreg[s] = *(const uint4*)(kg + ((size_t)(bh * T_ + j0n + r) * KC + c8 * 8));
        }
#pragma unroll
        for (int s = 0; s < 4; s++) {
            const int e = s * 256 + tgid;
            const int ch = e >> 3, k8 = e & 7;
            vreg[s] = *(const uint4*)(vtg + ((size_t)(bh * KC + ch) * T_ + j0n + k8 * 8));
        }
        if (tgid < 64) mreg = mask[b * T_ + j0n + tgid];
    }

    // ---- rel-k logits via MFMA (group 0 only; overlaps prologue loads) ----
    // rlog[r][d] = scale * q[i0+r] . relk[d];  B rows 9..15 are garbage ->
    // output cols 9..15 garbage (per-column independence), never read.
    if (grp == 0) {
        f32x4 racc = {};
#pragma unroll
        for (int ks = 0; ks < 4; ks++) {
            const int sw = ((ks * 4 + quad) ^ c7) * 8;
            const bf16x8 aq = *(const bf16x8*)(Qs + (row0 + c_) * 128 + sw);
            const bf16x8 bk = *(const bf16x8*)(Krel + c_ * 128 + sw);
            racc = __builtin_amdgcn_mfma_f32_16x16x32_bf16(aq, bk, racc, 0, 0, 0);
        }
        if (c_ < 9) {
#pragma unroll
            for (int r4 = 0; r4 < 4; r4++)
                rlog[row0 + quad * 4 + r4][c_] = racc[r4] * scale;
        }
    }

    // ---- write prologue tile to LDS (implicit vmcnt waits) ----
#pragma unroll
    for (int s = 0; s < 4; s++) {
        const int e = s * 256 + tgid;
        const int r = e >> 4, c8 = e & 15;
        *(uint4*)(Ks + r * 128 + ((c8 ^ (r & 7)) * 8)) = kreg[s];
    }
#pragma unroll
    for (int s = 0; s < 4; s++) {
        const int e = s * 256 + tgid;
        const int ch = e >> 3, k8 = e & 7;
        *(uint4*)(Vt + ch * 64 + ((k8 ^ (ch & 7)) * 8)) = vreg[s];
    }
    if (tgid < 64) msk[tgid] = mreg;
    __syncthreads();

    float m_run[4], l_run[4];
    f32x4 acco[8] = {};
#pragma unroll
    for (int r4 = 0; r4 < 4; r4++) { m_run[r4] = -1e30f; l_run[r4] = 0.f; }

    for (int tt = 0; tt < ntt; tt++) {
        const int t = 2 * tt + grp;
        const bool act = (t < ntl);          // group 1 may run a dummy last iter
        const int j0 = cstart + t * 64;
        const int tn = t + 2;
        const bool pf = (tn < ntl);
        const int j0n = cstart + tn * 64;

        // ---- issue next tile's loads early (latency hides under compute) ----
        if (pf) {
#pragma unroll
            for (int s = 0; s < 4; s++) {
                const int e = s * 256 + tgid;
                const int r = e >> 4, c8 = e & 15;
                kreg[s] = *(const uint4*)(kg + ((size_t)(bh * T_ + j0n + r) * KC + c8 * 8));
            }
#pragma unroll
            for (int s = 0; s < 4; s++) {
                const int e = s * 256 + tgid;
                const int ch = e >> 3, k8 = e & 7;
                vreg[s] = *(const uint4*)(vtg + ((size_t)(bh * KC + ch) * T_ + j0n + k8 * 8));
            }
            if (tgid < 64) mreg = mask[b * T_ + j0n + tgid];
        }

        if (act) {
            // ---- S = Q . K^T : 16 MFMAs per wave ----
            f32x4 accs[4] = {};
#pragma unroll
            for (int ks = 0; ks < 4; ks++) {
                const int sw = ((ks * 4 + quad) ^ c7) * 8;
                const bf16x8 aq = *(const bf16x8*)(Qs + (row0 + c_) * 128 + sw);
#pragma unroll
                for (int ct = 0; ct < 4; ct++) {
                    const bf16x8 bk = *(const bf16x8*)(Ks + (ct * 16 + c_) * 128 + sw);
                    accs[ct] = __builtin_amdgcn_mfma_f32_16x16x32_bf16(aq, bk, accs[ct], 0, 0, 0);
                }
            }

            // ---- online softmax on C-layout fragments ----
            float mskv[4];
#pragma unroll
            for (int ct = 0; ct < 4; ct++) mskv[ct] = msk[ct * 16 + c_];

            float alpha4[4];
#pragma unroll
            for (int r4 = 0; r4 < 4; r4++) {
                const int row = row0 + quad * 4 + r4;
                const float rm = rowm[row];
                const int dj = j0 - i0 + c_ - row;  // d at ct=0
                float sv[4];
                float mt = -3e38f;
#pragma unroll
                for (int ct = 0; ct < 4; ct++) {
                    const int d = dj + ct * 16;
                    const unsigned ad = (unsigned)((d < 0) ? -d : d);
                    float s;
                    if (rm != 0.f && mskv[ct] != 0.f && ad <= 256u) {
                        s = accs[ct][r4] * scale - lg[ad];
                        const unsigned dw = (unsigned)(d + 4);
                        if (dw <= 8u) s += rlog[row][dw];
                    } else {
                        s = NEG_;
                    }
                    sv[ct] = s;
                    mt = fmaxf(mt, s);
                }
                mt = fmaxf(mt, __shfl_xor(mt, 1));
                mt = fmaxf(mt, __shfl_xor(mt, 2));
                mt = fmaxf(mt, __shfl_xor(mt, 4));
                mt = fmaxf(mt, __shfl_xor(mt, 8));
                const float mnew = fmaxf(m_run[r4], mt);
                const float al = __expf(m_run[r4] - mnew);
                alpha4[r4] = al;
                m_run[r4] = mnew;

                const int row7 = row & 7;
                float lt = 0.f;
#pragma unroll
                for (int ct = 0; ct < 4; ct++) {
                    const float p = __expf(sv[ct] - mnew);
                    sv[ct] = p;
                    lt += p;
                    Ps[row * 64 + (((2 * ct + (c_ >> 3)) ^ row7) * 8) + c7] = f2b_rne(p);
                }
                lt += __shfl_xor(lt, 1);
                lt += __shfl_xor(lt, 2);
                lt += __shfl_xor(lt, 4);
                lt += __shfl_xor(lt, 8);
                l_run[r4] = l_run[r4] * al + lt;

                // pdiag: rescale (c_==0 lane) then adds — same-wave ds ops, in order
                if (c_ == 0) {
#pragma unroll
                    for (int dd = 0; dd < 9; dd++) pdiag[row][dd] *= al;
                }
#pragma unroll
                for (int ct = 0; ct < 4; ct++) {
                    const int d = dj + ct * 16;
                    const unsigned dw = (unsigned)(d + 4);
                    if (dw <= 8u) pdiag[row][dw] += sv[ct];
                }
            }

            // ---- O *= alpha ----
#pragma unroll
            for (int nt = 0; nt < 8; nt++)
#pragma unroll
                for (int r4 = 0; r4 < 4; r4++) acco[nt][r4] *= alpha4[r4];
        }

        __syncthreads();  // Ps visible within group

        if (act) {
            // ---- PV: 16 MFMAs per wave ----
#pragma unroll
            for (int kt = 0; kt < 2; kt++) {
                const int sw = ((kt * 4 + quad) ^ c7) * 8;
                const bf16x8 ap = *(const bf16x8*)(Ps + (row0 + c_) * 64 + sw);
#pragma unroll
                for (int nt = 0; nt < 8; nt++) {
                    const bf16x8 bv = *(const bf16x8*)(Vt + (nt * 16 + c_) * 64 + sw);
                    acco[nt] = __builtin_amdgcn_mfma_f32_16x16x32_bf16(ap, bv, acco[nt], 0, 0, 0);
                }
            }
        }

        __syncthreads();  // all Ks/Vt/Ps reads done -> safe to overwrite

        if (pf) {
#pragma unroll
            for (int s = 0; s < 4; s++) {
                const int e = s * 256 + tgid;
                const int r = e >> 4, c8 = e & 15;
                *(uint4*)(Ks + r * 128 + ((c8 ^ (r & 7)) * 8)) = kreg[s];
            }
#pragma unroll
            for (int s = 0; s < 4; s++) {
                const int e = s * 256 + tgid;
                const int ch = e >> 3, k8 = e & 7;
                *(uint4*)(Vt + ch * 64 + ((k8 ^ (ch & 7)) * 8)) = vreg[s];
            }
            if (tgid < 64) msk[tgid] = mreg;
        }

        __syncthreads();  // staged tile visible for next iteration
    }

    __syncthreads();

    // ---- merge group 1's state into group 0 (exact online-softmax combine) ----
    float* Ocomb = (float*)Ks2;  // 64x128 fp32 = 32 KB, exactly Ks2's footprint
    if (grp == 1) {
#pragma unroll
        for (int r4 = 0; r4 < 4; r4++) {
            const int row = row0 + quad * 4 + r4;
            if (c_ == 0) { m1s[row] = m_run[r4]; l1s[row] = l_run[r4]; }
#pragma unroll
            for (int nt = 0; nt < 8; nt++)
                Ocomb[row * 128 + nt * 16 + c_] = acco[nt][r4];
        }
    }
    __syncthreads();

    // ---- epilogue (group 0): combine, rel-v via pdiag, normalize, store ----
    if (grp == 0) {
#pragma unroll
        for (int r4 = 0; r4 < 4; r4++) {
            const int row = row0 + quad * 4 + r4;
            const int i = i0 + row;
            const float m0v = m_run[r4];
            const float m1v = m1s[row];
            const float mn  = fmaxf(m0v, m1v);
            const float a0  = __expf(m0v - mn);
            const float a1  = __expf(m1v - mn);
            const float l   = l_run[r4] * a0 + l1s[row] * a1;
            const float invl = 1.f / l;
            float pd[9];
#pragma unroll
            for (int dd = 0; dd < 9; dd++) {
                const int j = i + dd - 4;
                pd[dd] = (j >= 0 && j < T_)
                    ? (pdiag2[0][row][dd] * a0 + pdiag2[1][row][dd] * a1) : 0.f;
            }
            ushort* ob = outp + ((size_t)(b * T_ + i) * H_ + h) * KC;
#pragma unroll
            for (int nt = 0; nt < 8; nt++) {
                const int col = nt * 16 + c_;
                float o = acco[nt][r4] * a0 + Ocomb[row * 128 + col] * a1;
#pragma unroll
                for (int dd = 0; dd < 9; dd++) o += pd[dd] * relv_s[dd * 128 + col];
                ob[col] = f2b_rne(o * invl);
            }
        }
    }
}

// ---------------------------------------------------------------------------
extern "C" void kernel_launch(void* const* d_in, const int* in_sizes, int n_in,
                              void* d_out, int out_size, void* d_ws, size_t ws_size,
                              hipStream_t stream)
{
    const float* x    = (const float*)d_in[0];
    const float* c    = (const float*)d_in[1];
    const float* am   = (const float*)d_in[2];
    const float* Wq   = (const float*)d_in[3];
    const float* bq   = (const float*)d_in[4];
    const float* Wk   = (const float*)d_in[5];
    const float* bk   = (const float*)d_in[6];
    const float* Wv   = (const float*)d_in[7];
    const float* bv   = (const float*)d_in[8];
    const float* Wo   = (const float*)d_in[9];
    const float* bo   = (const float*)d_in[10];
    const float* relk = (const float*)d_in[11];
    const float* relv = (const float*)d_in[12];

    float* out = (float*)d_out;
    char* w8 = (char*)d_ws;
    ushort* qb  = (ushort*)(w8);
    ushort* kb  = (ushort*)(w8 + (4u << 20));
    ushort* vtb = (ushort*)(w8 + (8u << 20));   // [B,H,KC,T]
    ushort* ab  = (ushort*)(w8 + (12u << 20));
    ushort* xb  = (ushort*)(w8 + (16u << 20));
    ushort* cb  = (ushort*)(w8 + (20u << 20));
    ushort* Wqb = (ushort*)(w8 + (24u << 20));
    ushort* Wkb = Wqb + 262144;
    ushort* Wvb = Wkb + 262144;
    ushort* Wob = Wvb + 262144;

    cvt_all<<<2560, 256, 0, stream>>>(x, c, Wq, Wk, Wv, Wo, xb, cb, Wqb, Wkb, Wvb, Wob);

    dim3 ggrid(4096 / GB, D_ / GB);  // (64, 8)
    gemm_mfma<<<ggrid, 256, 0, stream>>>(xb, Wqb, bq, qb, 1);
    gemm_mfma<<<ggrid, 256, 0, stream>>>(cb, Wkb, bk, kb, 1);
    gemm_mfma<<<ggrid, 256, 0, stream>>>(cb, Wvb, bv, vtb, 2);

    attn_mfma<<<dim3(16, 16), 512, 0, stream>>>(qb, kb, vtb, am, relk, relv, ab);

    gemm_mfma<<<ggrid, 256, 0, stream>>>(ab, Wob, bo, (void*)out, 0);
}